// Round 6
// baseline (83.236 us; speedup 1.0000x reference)
//
#include <hip/hip_runtime.h>
#include <math.h>

#define HH 256
#define WW 256
#define CC 3
#define HW (HH*WW)
#define PW 264              // padded row stride (floats): cols -4..259
#define NROWS (4*CC*HH)     // 3072 (b,c,row) rows

__device__ __forceinline__ int reflect(int v, int n) {
    v = (v < 0) ? -v : v;
    v = (v > n - 1) ? (2 * (n - 1) - v) : v;
    return v;
}

// dense index for the 16 distinct r^2 values in a 9x9 window
__device__ __forceinline__ constexpr int r2idx(int r2) {
    switch (r2) {
        case 0:  return 0;  case 1:  return 1;  case 2:  return 2;  case 4:  return 3;
        case 5:  return 4;  case 8:  return 5;  case 9:  return 6;  case 10: return 7;
        case 13: return 8;  case 16: return 9;  case 17: return 10; case 18: return 11;
        case 20: return 12; case 25: return 13; case 26: return 14; default: return 15; // 32
    }
}

// ---- column-pad only: pw[row][i] = x[row][reflect(i-4)], i in 0..263 ----
// one wave per image row; 4 rows per 256-thread block; grid 768 blocks.
__global__ __launch_bounds__(256) void pad_kernel(
    const float* __restrict__ x, float* __restrict__ pw)
{
    const int row  = blockIdx.x * 4 + (threadIdx.x >> 6);  // 0..3071
    const int lane = threadIdx.x & 63;
    const float* src = x + (size_t)row * WW;
    float* dst = pw + (size_t)row * PW;
    // interior: dst cols 4..259 <- src cols 0..255 (both 16B-aligned)
    *(float4*)(dst + 4 + lane * 4) = *(const float4*)(src + lane * 4);
    // 8 reflected edge columns: dst cols 0..3 and 260..263
    if (lane < 8) {
        const int i = (lane < 4) ? lane : (256 + lane);    // 0..3, 260..263
        dst[i] = src[reflect(i - 4, WW)];
    }
}

// ---- main: one thread = 4 horizontal outputs of ONE channel ----
// 256 threads/block = 4 waves; wave -> one (c,y) row; grid (192,4) = 768 blocks
// -> 3072 waves = 12 waves/CU (grid-limited). Branch-free, all float4 loads.
__global__ __launch_bounds__(256, 3) void adaptive_log_kernel(
    const float* __restrict__ pin, const float* __restrict__ foa,
    float* __restrict__ out)
{
    const int tid  = threadIdx.x;
    const int lane = tid & 63;
    const int x0   = lane * 4;
    const int gw   = blockIdx.x * 4 + (tid >> 6);   // 0..767
    const int c    = gw >> 8;                       // 0..2
    const int y    = gw & 255;                      // 0..255
    const int b    = blockIdx.y;

    // reflected row offsets (wave-uniform y), into column-padded buffer
    const float* base = pin + (size_t)((b * CC + c) * HH) * PW + x0;
    int ro[9];
    #pragma unroll
    for (int i = 0; i < 9; ++i)
        ro[i] = reflect(y + i - 4, HH) * PW;

    // ---- weight tables for the 4 output pixels: 1 exp + power chain each ----
    const float fx = foa[2 * b + 0];
    const float fy = foa[2 * b + 1];
    float w[4][16];
    #pragma unroll
    for (int o = 0; o < 4; ++o) {
        const float ddx = (float)(x0 + o) - fx;
        const float ddy = (float)y - fy;
        const float dist = sqrtf(ddx * ddx + ddy * ddy);
        const float dn = dist * (1.0f / 362.03867196751236f); // 1/sqrt(2*256^2)
        const float sigma = 0.5f + 9.5f * dn;
        const float s2 = sigma * sigma;
        const float inv2s2 = 0.5f / s2;
        const float common = (-1.0f / (float)M_PI) / (s2 * s2) * sqrtf(sigma) * dist;
        const float q   = __expf(-inv2s2);
        const float q2  = q * q;
        const float q4  = q2 * q2;
        const float q5  = q4 * q;
        const float q8  = q4 * q4;
        const float q16 = q8 * q8;
        const float ee[16]  = {1.0f, q, q2, q4, q5, q8, q8*q, q8*q2, q8*q5,
                               q16, q16*q, q16*q2, q16*q4, q16*q8*q, q16*q8*q2, q16*q16};
        const float r2v[16] = {0,1,2,4,5,8,9,10,13,16,17,18,20,25,26,32};
        const float cb = common * inv2s2;
        #pragma unroll
        for (int k = 0; k < 16; ++k)
            w[o][k] = (common - r2v[k] * cb) * ee[k];
    }

    // ---- 9x9 conv, single channel, 3 aligned float4 loads per window row ----
    float acc[4] = {0.f, 0.f, 0.f, 0.f};
    #pragma unroll
    for (int i = 0; i < 9; ++i) {
        const float* rp = base + ro[i];
        const float4 A = *(const float4*)(rp);
        const float4 B = *(const float4*)(rp + 4);
        const float4 C4 = *(const float4*)(rp + 8);
        const float f[12] = {A.x,A.y,A.z,A.w, B.x,B.y,B.z,B.w, C4.x,C4.y,C4.z,C4.w};
        const int dy2 = (i - 4) * (i - 4);
        #pragma unroll
        for (int o = 0; o < 4; ++o) {
            float s = 0.f;
            #pragma unroll
            for (int m = 0; m < 9; ++m)
                s += w[o][r2idx(dy2 + (m - 4) * (m - 4))] * f[o + m];
            acc[o] += s;
        }
    }

    float* ob = out + (size_t)(b * CC + c) * HW + y * WW + x0;
    *(float4*)ob = make_float4(acc[0], acc[1], acc[2], acc[3]);
}

extern "C" void kernel_launch(void* const* d_in, const int* in_sizes, int n_in,
                              void* d_out, int out_size, void* d_ws, size_t ws_size,
                              hipStream_t stream) {
    const float* x   = (const float*)d_in[0];   // [4,3,256,256] f32
    const float* foa = (const float*)d_in[1];   // [4,2] f32
    float* out = (float*)d_out;                 // [4,3,256,256] f32
    float* pw  = (float*)d_ws;                  // col-padded input: 3072*264 floats (~3.2 MB)

    pad_kernel<<<dim3(NROWS / 4), dim3(256), 0, stream>>>(x, pw);
    adaptive_log_kernel<<<dim3(192, 4), dim3(256), 0, stream>>>(pw, foa, out);
}